// Round 3
// baseline (7267.372 us; speedup 1.0000x reference)
//
#include <hip/hip_runtime.h>
#include <hip/hip_bf16.h>
#include <math.h>

typedef __bf16 bf16;
typedef __bf16 bf16x8 __attribute__((ext_vector_type(8)));
typedef float f32x4 __attribute__((ext_vector_type(4)));
typedef unsigned short u16;

#define S_ 197
#define BATCH 32
#define ROWS (BATCH * S_)       // 6304
#define NPATCH 196
#define PROWS (BATCH * NPATCH)  // 6272
#define HROWS 3152              // ROWS/2

// dual-dtype load: inputs may be bf16 or f32 (detected at runtime on device)
__device__ __forceinline__ float ldf(const void* p, long i, int isf32) {
  return isf32 ? ((const float*)p)[i] : (float)(((const bf16*)p)[i]);
}

// ------------------------------------------------------------- dtype detect
__global__ void detect_kernel(const void* __restrict__ img, int* __restrict__ flag) {
  if (threadIdx.x == 0) {
    const u16* p = (const u16*)img;
    int f32 = 0;
    for (int i = 0; i < 1024; i++) {
      int e = (p[i] >> 7) & 0xFF;   // bf16 exponent field
      if (e >= 135) f32 = 1;        // |val| >= 256: impossible for N(0,1) bf16
    }
    *flag = f32;
  }
}

// ---------------------------------------------------------------- patchify
__global__ __launch_bounds__(256) void patchify_kernel(const void* __restrict__ img,
                                                       bf16* __restrict__ patches,
                                                       const int* __restrict__ flagp) {
  int isf32 = *flagp;
  int idx = blockIdx.x * 256 + threadIdx.x;  // < 6272*768
  int m = idx / 768, pd = idx - m * 768;
  int b = m / NPATCH, n = m - b * NPATCH;
  int gy = n / 14, gx = n - gy * 14;
  int c = pd >> 8, r = (pd >> 4) & 15, col = pd & 15;
  long src = ((long)(b * 3 + c) * 224 + gy * 16 + r) * 224 + gx * 16 + col;
  patches[idx] = (bf16)ldf(img, src, isf32);
}

// ------------------------------------------------------------- cls+pos fill
__global__ __launch_bounds__(256) void cls_fill_kernel(const void* __restrict__ cls_t,
                                                       const void* __restrict__ pos,
                                                       float* __restrict__ x,
                                                       const int* __restrict__ flagp) {
  int isf32 = *flagp;
  int idx = blockIdx.x * 256 + threadIdx.x;  // < 32*768
  int b = idx / 768, e = idx - b * 768;
  x[(size_t)(b * S_) * 768 + e] = ldf(cls_t, e, isf32) + ldf(pos, e, isf32);
}

// ---------------------------------------------------------------- layernorm
__global__ __launch_bounds__(256) void ln_kernel(const float* __restrict__ x,
                                                 bf16* __restrict__ h) {
  int row = blockIdx.x;
  const float* xr = x + (size_t)row * 768;
  int tid = threadIdx.x;
  float v0 = xr[tid], v1 = xr[tid + 256], v2 = xr[tid + 512];
  float a = v0 + v1 + v2;
  float b = v0 * v0 + v1 * v1 + v2 * v2;
  for (int off = 32; off; off >>= 1) {
    a += __shfl_down(a, off, 64);
    b += __shfl_down(b, off, 64);
  }
  __shared__ float sa[4], sb[4];
  int wave = tid >> 6;
  if ((tid & 63) == 0) { sa[wave] = a; sb[wave] = b; }
  __syncthreads();
  float mu = (sa[0] + sa[1] + sa[2] + sa[3]) * (1.f / 768.f);
  float var = (sb[0] + sb[1] + sb[2] + sb[3]) * (1.f / 768.f) - mu * mu;
  float rs = rsqrtf(fmaxf(var, 0.f) + 1e-5f);
  bf16* hr = h + (size_t)row * 768;
  hr[tid] = (bf16)((v0 - mu) * rs);
  hr[tid + 256] = (bf16)((v1 - mu) * rs);
  hr[tid + 512] = (bf16)((v2 - mu) * rs);
}

// ---------------------------------------------------------------- GEMM 64x64
// C[M,N] = A[M,K] @ B[K,N]; A is internal bf16 (row stride lda); B is an
// input tensor (bf16 or f32 per flag), element offset boff.
// MODE 0: patch embed -> fp32 x with row remap, + bias + pos_emb(aux)
// MODE 1: qkv -> bf16, cols < 768 scaled 0.125
// MODE 2: residual -> fp32 out += acc (+ optional bias)
// MODE 3: gelu(acc + bias) -> bf16
#define LSTR 72
template <int MODE>
__global__ __launch_bounds__(256) void gemm64(const bf16* __restrict__ A,
                                              const void* __restrict__ Bw,
                                              const void* __restrict__ bias,
                                              const void* __restrict__ aux,
                                              void* __restrict__ outp,
                                              int M, int N, int K, int lda,
                                              long boff, long biasoff,
                                              const int* __restrict__ flagp) {
  int isf32 = *flagp;
  __shared__ bf16 As[64 * LSTR];
  __shared__ bf16 Bs[64 * LSTR];
  int tid = threadIdx.x;
  int wave = tid >> 6, lane = tid & 63;
  int q = lane >> 4, r = lane & 15;
  int m0 = blockIdx.y * 64, n0 = blockIdx.x * 64;
  int wm = (wave >> 1) * 32, wn = (wave & 1) * 32;
  int a_row = tid >> 2, a_kc = (tid & 3) << 3;
  int b_n = tid & 63, b_kc = (tid >> 6) << 3;
  f32x4 acc[2][2] = {};
  const int agm = m0 + a_row;
  const bool aval = (agm < M);
  const bf16* Ap = A + (size_t)agm * lda + a_kc;
  const long bidx = boff + (long)b_kc * N + n0 + b_n;

  for (int k0 = 0; k0 < K; k0 += 32) {
    uint4 av = make_uint4(0, 0, 0, 0);
    if (aval) __builtin_memcpy(&av, Ap + k0, 16);
    alignas(16) bf16 bvv[8];
    if (isf32) {
      const float* bp = (const float*)Bw + bidx + (long)k0 * N;
#pragma unroll
      for (int j = 0; j < 8; j++) bvv[j] = (bf16)bp[(long)j * N];
    } else {
      const bf16* bp = (const bf16*)Bw + bidx + (long)k0 * N;
#pragma unroll
      for (int j = 0; j < 8; j++) bvv[j] = bp[(long)j * N];
    }
    __syncthreads();
    __builtin_memcpy(&As[a_row * LSTR + a_kc], &av, 16);
    __builtin_memcpy(&Bs[b_n * LSTR + b_kc], bvv, 16);
    __syncthreads();
    bf16x8 af0, af1, bf0, bf1;
    __builtin_memcpy(&af0, &As[(wm + r) * LSTR + q * 8], 16);
    __builtin_memcpy(&af1, &As[(wm + 16 + r) * LSTR + q * 8], 16);
    __builtin_memcpy(&bf0, &Bs[(wn + r) * LSTR + q * 8], 16);
    __builtin_memcpy(&bf1, &Bs[(wn + 16 + r) * LSTR + q * 8], 16);
    acc[0][0] = __builtin_amdgcn_mfma_f32_16x16x32_bf16(af0, bf0, acc[0][0], 0, 0, 0);
    acc[0][1] = __builtin_amdgcn_mfma_f32_16x16x32_bf16(af0, bf1, acc[0][1], 0, 0, 0);
    acc[1][0] = __builtin_amdgcn_mfma_f32_16x16x32_bf16(af1, bf0, acc[1][0], 0, 0, 0);
    acc[1][1] = __builtin_amdgcn_mfma_f32_16x16x32_bf16(af1, bf1, acc[1][1], 0, 0, 0);
  }

#pragma unroll
  for (int i = 0; i < 2; i++) {
#pragma unroll
    for (int jt = 0; jt < 2; jt++) {
      int col = n0 + wn + jt * 16 + r;
#pragma unroll
      for (int v = 0; v < 4; v++) {
        int m = m0 + wm + i * 16 + q * 4 + v;
        if (m >= M) continue;
        float val = acc[i][jt][v];
        if (MODE == 0) {
          int bb = m / NPATCH, pn = m - bb * NPATCH + 1;
          val += ldf(bias, col, isf32) + ldf(aux, (long)pn * 768 + col, isf32);
          ((float*)outp)[((size_t)bb * S_ + pn) * 768 + col] = val;
        } else if (MODE == 1) {
          if (col < 768) val *= 0.125f;
          ((bf16*)outp)[(size_t)m * N + col] = (bf16)val;
        } else if (MODE == 2) {
          if (bias) val += ldf(bias, biasoff + col, isf32);
          ((float*)outp)[(size_t)m * N + col] += val;
        } else {
          val += ldf(bias, biasoff + col, isf32);
          float t = val + 0.044715f * val * val * val;
          float g = 0.5f * val * (1.0f + tanhf(0.7978845608028654f * t));
          ((bf16*)outp)[(size_t)m * N + col] = (bf16)g;
        }
      }
    }
  }
}

// ---------------------------------------------------------------- attention
// one block per (batch, head); q pre-scaled 0.125 in qkv epilogue.
// Output written IN-PLACE over this (b,h)'s q-slice (row tid's q is read only
// by thread tid before its own write — no cross-thread hazard).
__global__ __launch_bounds__(256) void attn_kernel(bf16* __restrict__ qkv) {
  int bh = blockIdx.x;
  int b = bh / 12, hh = bh - b * 12;
  __shared__ bf16 ks[S_ * 64];
  __shared__ bf16 vs[S_ * 64];
  int tid = threadIdx.x;
  bf16* base = qkv + (size_t)b * S_ * 2304 + hh * 64;
  for (int ch = tid; ch < S_ * 8; ch += 256) {
    int row = ch >> 3, c8 = (ch & 7) << 3;
    uint4 kv, vv;
    __builtin_memcpy(&kv, base + (size_t)row * 2304 + 768 + c8, 16);
    __builtin_memcpy(&vv, base + (size_t)row * 2304 + 1536 + c8, 16);
    __builtin_memcpy(&ks[row * 64 + c8], &kv, 16);
    __builtin_memcpy(&vs[row * 64 + c8], &vv, 16);
  }
  __syncthreads();
  if (tid < S_) {
    float qf[64];
#pragma unroll
    for (int c8 = 0; c8 < 8; c8++) {
      bf16x8 qv;
      __builtin_memcpy(&qv, base + (size_t)tid * 2304 + c8 * 8, 16);
#pragma unroll
      for (int e = 0; e < 8; e++) qf[c8 * 8 + e] = (float)qv[e];
    }
    float mx = -1e30f, l = 0.f;
    float oacc[64];
#pragma unroll
    for (int i = 0; i < 64; i++) oacc[i] = 0.f;
    for (int j = 0; j < S_; j++) {
      float s = 0.f;
#pragma unroll
      for (int c8 = 0; c8 < 8; c8++) {
        bf16x8 kv;
        __builtin_memcpy(&kv, &ks[j * 64 + c8 * 8], 16);
#pragma unroll
        for (int e = 0; e < 8; e++) s += qf[c8 * 8 + e] * (float)kv[e];
      }
      float mn = fmaxf(mx, s);
      float cf = __expf(mx - mn);
      float p = __expf(s - mn);
      l = l * cf + p;
      mx = mn;
#pragma unroll
      for (int c8 = 0; c8 < 8; c8++) {
        bf16x8 vv;
        __builtin_memcpy(&vv, &vs[j * 64 + c8 * 8], 16);
#pragma unroll
        for (int e = 0; e < 8; e++)
          oacc[c8 * 8 + e] = oacc[c8 * 8 + e] * cf + p * (float)vv[e];
      }
    }
    float inv = 1.f / l;
    bf16* orow = base + (size_t)tid * 2304;  // overwrite own q slice
#pragma unroll
    for (int c8 = 0; c8 < 8; c8++) {
      alignas(16) bf16 pk[8];
#pragma unroll
      for (int e = 0; e < 8; e++) pk[e] = (bf16)(oacc[c8 * 8 + e] * inv);
      __builtin_memcpy(orow + c8 * 8, pk, 16);
    }
  }
}

// ------------------------------------------------------------- final LN+head
// Output dtype follows the input dtype (f32 problem -> f32 out, bf16 -> bf16).
__global__ __launch_bounds__(256) void head_kernel(const float* __restrict__ x,
                                                   const void* __restrict__ g,
                                                   const void* __restrict__ bb,
                                                   const void* __restrict__ hw,
                                                   const void* __restrict__ hb,
                                                   void* __restrict__ out,
                                                   const int* __restrict__ flagp) {
  int isf32 = *flagp;
  int b = blockIdx.x;
  const float* xr = x + (size_t)b * S_ * 768;  // row s=0 (cls)
  int tid = threadIdx.x;
  float v0 = xr[tid], v1 = xr[tid + 256], v2 = xr[tid + 512];
  float a = v0 + v1 + v2;
  float s2 = v0 * v0 + v1 * v1 + v2 * v2;
  for (int off = 32; off; off >>= 1) {
    a += __shfl_down(a, off, 64);
    s2 += __shfl_down(s2, off, 64);
  }
  __shared__ float sa[4], sb[4];
  int wave = tid >> 6;
  if ((tid & 63) == 0) { sa[wave] = a; sb[wave] = s2; }
  __syncthreads();
  float mu = (sa[0] + sa[1] + sa[2] + sa[3]) * (1.f / 768.f);
  float var = (sb[0] + sb[1] + sb[2] + sb[3]) * (1.f / 768.f) - mu * mu;
  float rs = rsqrtf(fmaxf(var, 0.f) + 1e-5f);
  __shared__ float cls[768];
  cls[tid] = (v0 - mu) * rs * ldf(g, tid, isf32) + ldf(bb, tid, isf32);
  cls[tid + 256] = (v1 - mu) * rs * ldf(g, tid + 256, isf32) + ldf(bb, tid + 256, isf32);
  cls[tid + 512] = (v2 - mu) * rs * ldf(g, tid + 512, isf32) + ldf(bb, tid + 512, isf32);
  __syncthreads();
  float p[10];
#pragma unroll
  for (int c = 0; c < 10; c++) p[c] = 0.f;
  for (int e = tid; e < 768; e += 256) {
    float cv = cls[e];
#pragma unroll
    for (int c = 0; c < 10; c++) p[c] += cv * ldf(hw, (long)e * 10 + c, isf32);
  }
#pragma unroll
  for (int c = 0; c < 10; c++)
    for (int off = 32; off; off >>= 1) p[c] += __shfl_down(p[c], off, 64);
  __shared__ float red[4][10];
  if ((tid & 63) == 0) {
#pragma unroll
    for (int c = 0; c < 10; c++) red[wave][c] = p[c];
  }
  __syncthreads();
  if (tid < 10) {
    float val = red[0][tid] + red[1][tid] + red[2][tid] + red[3][tid] +
                ldf(hb, tid, isf32);
    if (isf32) ((float*)out)[b * 10 + tid] = val;
    else       ((bf16*)out)[b * 10 + tid] = (bf16)val;
  }
}

// ------------------------------------------------------------------ launcher
extern "C" void kernel_launch(void* const* d_in, const int* in_sizes, int n_in,
                              void* d_out, int out_size, void* d_ws, size_t ws_size,
                              hipStream_t stream) {
  const void* img     = d_in[0];
  const void* patch_w = d_in[1];
  const void* patch_b = d_in[2];
  const void* cls_t   = d_in[3];
  const void* pos     = d_in[4];
  const void* qkv_w   = d_in[5];
  const void* fc_w    = d_in[6];
  const void* mlp_w1  = d_in[7];
  const void* mlp_b1  = d_in[8];
  const void* mlp_w2  = d_in[9];
  const void* mlp_b2  = d_in[10];
  const void* ln_g    = d_in[11];
  const void* ln_b    = d_in[12];
  const void* head_w  = d_in[13];
  const void* head_b  = d_in[14];

  char* ws = (char*)d_ws;
  // compact layout (58.1 MB total):
  //   x   fp32  [6304,768]   @ 0          (19,365,888 B)
  //   h   bf16  [6304,768]   @ 19365888   ( 9,682,944 B)
  //   qkv bf16  [6304,2304]  @ 29048832   (29,048,832 B)  (attn out in-place in q)
  //   flag int               @ 58097664
  float* x   = (float*)ws;
  bf16* h    = (bf16*)(ws + 19365888);
  bf16* qkvb = (bf16*)(ws + 29048832);
  int* flag  = (int*)(ws + 58097664);
  bf16* patches = qkvb;  // alias (free before layer loop)
  bf16* mlpbuf  = qkvb;  // alias (qkv dead during MLP)

  detect_kernel<<<1, 64, 0, stream>>>(img, flag);
  patchify_kernel<<<PROWS * 768 / 256, 256, 0, stream>>>(img, patches, flag);
  cls_fill_kernel<<<BATCH * 768 / 256, 256, 0, stream>>>(cls_t, pos, x, flag);
  gemm64<0><<<dim3(12, 98), 256, 0, stream>>>(patches, patch_w, patch_b, pos, x,
                                              PROWS, 768, 768, 768, 0, 0, flag);
  for (int l = 0; l < 12; ++l) {
    ln_kernel<<<ROWS, 256, 0, stream>>>(x, h);
    gemm64<1><<<dim3(36, 99), 256, 0, stream>>>(h, qkv_w, nullptr, nullptr, qkvb,
                                                ROWS, 2304, 768, 768,
                                                (long)l * 768 * 2304, 0, flag);
    attn_kernel<<<BATCH * 12, 256, 0, stream>>>(qkvb);
    gemm64<2><<<dim3(12, 99), 256, 0, stream>>>(qkvb, fc_w, nullptr, nullptr, x,
                                                ROWS, 768, 768, 2304,
                                                (long)l * 768 * 768, 0, flag);
    ln_kernel<<<ROWS, 256, 0, stream>>>(x, h);
    for (int half = 0; half < 2; ++half) {
      gemm64<3><<<dim3(48, 50), 256, 0, stream>>>(
          h + (size_t)half * HROWS * 768, mlp_w1, mlp_b1, nullptr, mlpbuf,
          HROWS, 3072, 768, 768, (long)l * 768 * 3072, (long)l * 3072, flag);
      gemm64<2><<<dim3(12, 50), 256, 0, stream>>>(
          mlpbuf, mlp_w2, mlp_b2, nullptr, x + (size_t)half * HROWS * 768,
          HROWS, 768, 3072, 3072, (long)l * 3072 * 768, (long)l * 768, flag);
    }
  }
  head_kernel<<<BATCH, 256, 0, stream>>>(x, ln_g, ln_b, head_w, head_b,
                                         d_out, flag);
}

// Round 5
// 4752.935 us; speedup vs baseline: 1.5290x; 1.5290x over previous
//
#include <hip/hip_runtime.h>
#include <hip/hip_bf16.h>
#include <math.h>

typedef __bf16 bf16;
typedef __bf16 bf16x8 __attribute__((ext_vector_type(8)));
typedef float f32x4 __attribute__((ext_vector_type(4)));
typedef unsigned short u16;
typedef unsigned int u32;

#define S_ 197
#define BATCH 32
#define ROWS (BATCH * S_)       // 6304
#define NPATCH 196
#define PROWS (BATCH * NPATCH)  // 6272
#define HROWS 3152              // ROWS/2

// async 16B global->LDS (gfx950). lds dst must be wave-uniform base; HW adds lane*16.
__device__ __forceinline__ void async_ld16(const bf16* g, const bf16* lds_base) {
  __builtin_amdgcn_global_load_lds(
      (const __attribute__((address_space(1))) u32*)(uintptr_t)g,
      (__attribute__((address_space(3))) u32*)(u32)(uintptr_t)lds_base, 16, 0, 0);
}

// ---------------------------------------------------------------- patchify
__global__ __launch_bounds__(256) void patchify_kernel(const float* __restrict__ img,
                                                       bf16* __restrict__ patches) {
  int idx = blockIdx.x * 256 + threadIdx.x;  // < 6272*768
  int m = idx / 768, pd = idx - m * 768;
  int b = m / NPATCH, n = m - b * NPATCH;
  int gy = n / 14, gx = n - gy * 14;
  int c = pd >> 8, r = (pd >> 4) & 15, col = pd & 15;
  long src = ((long)(b * 3 + c) * 224 + gy * 16 + r) * 224 + gx * 16 + col;
  patches[idx] = (bf16)img[src];
}

// ------------------------------------------------------------- cls+pos fill
__global__ __launch_bounds__(256) void cls_fill_kernel(const float* __restrict__ cls_t,
                                                       const float* __restrict__ pos,
                                                       float* __restrict__ x) {
  int idx = blockIdx.x * 256 + threadIdx.x;  // < 32*768
  int b = idx / 768, e = idx - b * 768;
  x[(size_t)(b * S_) * 768 + e] = cls_t[e] + pos[e];
}

// ---------------------------------------------------------------- layernorm
__global__ __launch_bounds__(256) void ln_kernel(const float* __restrict__ x,
                                                 bf16* __restrict__ h) {
  int row = blockIdx.x;
  const float* xr = x + (size_t)row * 768;
  int tid = threadIdx.x;
  float v0 = xr[tid], v1 = xr[tid + 256], v2 = xr[tid + 512];
  float a = v0 + v1 + v2;
  float b = v0 * v0 + v1 * v1 + v2 * v2;
  for (int off = 32; off; off >>= 1) {
    a += __shfl_down(a, off, 64);
    b += __shfl_down(b, off, 64);
  }
  __shared__ float sa[4], sb[4];
  int wave = tid >> 6;
  if ((tid & 63) == 0) { sa[wave] = a; sb[wave] = b; }
  __syncthreads();
  float mu = (sa[0] + sa[1] + sa[2] + sa[3]) * (1.f / 768.f);
  float var = (sb[0] + sb[1] + sb[2] + sb[3]) * (1.f / 768.f) - mu * mu;
  float rs = rsqrtf(fmaxf(var, 0.f) + 1e-5f);
  bf16* hr = h + (size_t)row * 768;
  hr[tid] = (bf16)((v0 - mu) * rs);
  hr[tid + 256] = (bf16)((v1 - mu) * rs);
  hr[tid + 512] = (bf16)((v2 - mu) * rs);
}

// ---------------------------------------------- transpose-convert f32 W[K][N] -> bf16 WT[N][K]
__device__ __forceinline__ void convT_tile(const float* __restrict__ src,
                                           bf16* __restrict__ dst, int Kr, int Nr,
                                           int tk, int tn, float* __restrict__ Ls) {
  int t = threadIdx.x;
  int a = t >> 3, c = t & 7;
  float4 v = *(const float4*)(src + (size_t)(tk * 32 + a) * Nr + tn * 32 + c * 4);
  Ls[a * 33 + c * 4 + 0] = v.x;
  Ls[a * 33 + c * 4 + 1] = v.y;
  Ls[a * 33 + c * 4 + 2] = v.z;
  Ls[a * 33 + c * 4 + 3] = v.w;
  __syncthreads();
  alignas(8) bf16 o[4];
#pragma unroll
  for (int i = 0; i < 4; i++) o[i] = (bf16)Ls[(c * 4 + i) * 33 + a];
  __builtin_memcpy(dst + (size_t)(tn * 32 + a) * Kr + tk * 32 + c * 4, o, 8);
}

__global__ __launch_bounds__(256) void convT_single(const float* __restrict__ src,
                                                    bf16* __restrict__ dst,
                                                    int Kr, int Nr) {
  __shared__ float Ls[32 * 33];
  int ntn = Nr / 32;
  int tk = blockIdx.x / ntn, tn = blockIdx.x % ntn;
  convT_tile(src, dst, Kr, Nr, tk, tn, Ls);
}

// one launch per layer: qkv_w, fc_w, mlp_w1, mlp_w2 slices -> wbuf
__global__ __launch_bounds__(256) void convT_layer(const float* __restrict__ qkvw,
                                                   const float* __restrict__ fcw,
                                                   const float* __restrict__ w1,
                                                   const float* __restrict__ w2,
                                                   bf16* __restrict__ wbuf) {
  __shared__ float Ls[32 * 33];
  int bid = blockIdx.x;
  const float* src;
  bf16* dst;
  int Kr, Nr;
  if (bid < 1728) { Kr = 768; Nr = 2304; src = qkvw; dst = wbuf; }
  else if (bid < 2304) { bid -= 1728; Kr = 768; Nr = 768; src = fcw; dst = wbuf + 1769472; }
  else if (bid < 4608) { bid -= 2304; Kr = 768; Nr = 3072; src = w1; dst = wbuf + 2359296; }
  else { bid -= 4608; Kr = 3072; Nr = 768; src = w2; dst = wbuf + 4718592; }
  int ntn = Nr / 32;
  convT_tile(src, dst, Kr, Nr, bid / ntn, bid % ntn, Ls);
}

// ------------------------------------------------------------- GEMM epilogue (shared)
template <int MODE>
__device__ __forceinline__ void epilogue_store(float val, int m, int col, int N,
                                               const float* __restrict__ bias,
                                               const float* __restrict__ aux,
                                               void* __restrict__ outp) {
  if (MODE == 0) {  // patch embed -> f32 x, row remap, +bias +pos
    int bb = m / NPATCH, pn = m - bb * NPATCH + 1;
    val += bias[col] + aux[(size_t)pn * 768 + col];
    ((float*)outp)[((size_t)bb * S_ + pn) * 768 + col] = val;
  } else if (MODE == 1) {  // qkv -> bf16, q cols scaled
    if (col < 768) val *= 0.125f;
    ((bf16*)outp)[(size_t)m * N + col] = (bf16)val;
  } else if (MODE == 2) {  // residual += (+bias)
    if (bias) val += bias[col];
    ((float*)outp)[(size_t)m * N + col] += val;
  } else {  // gelu(acc+bias) -> bf16 (R3-proven tanhf form)
    val += bias[col];
    float t = val + 0.044715f * val * val * val;
    float g = 0.5f * val * (1.0f + tanhf(0.7978845608028654f * t));
    ((bf16*)outp)[(size_t)m * N + col] = (bf16)g;
  }
}

// --------------------------------- GEMM 128x128, double-buffered LDS prefetch
// C[M,N] = A[M,K](bf16, stride lda) @ BT[N][K](bf16)^T ; f32 accum.
// Loads for tile k+1 target the OTHER buffer: no WAR hazard on live LDS data.
template <int MODE>
__global__ __launch_bounds__(256) void gemm128(const bf16* __restrict__ A,
                                               const bf16* __restrict__ BT,
                                               const float* __restrict__ bias,
                                               const float* __restrict__ aux,
                                               void* __restrict__ outp,
                                               int M, int N, int K, int lda) {
  __shared__ bf16 As[2][128 * 32];
  __shared__ bf16 Bs[2][128 * 32];
  int tid = threadIdx.x, wave = tid >> 6, lane = tid & 63;
  int q = lane >> 4, r = lane & 15;
  int m0 = blockIdx.y * 128, n0 = blockIdx.x * 128;
  int wm = (wave >> 1) * 64, wn = (wave & 1) * 64;
  int srow = lane >> 2, scol = (lane & 3) * 8;
  int coff = (wave * 2) * 512;  // wave-uniform LDS chunk offset (elements)
  f32x4 acc[4][4] = {};
  const bf16* Ap[2];
  const bf16* Bp[2];
#pragma unroll
  for (int p = 0; p < 2; p++) {
    int c = wave * 2 + p;
    int ar = m0 + c * 16 + srow;
    if (ar > M - 1) ar = M - 1;
    Ap[p] = A + (size_t)ar * lda + scol;
    Bp[p] = BT + (size_t)(n0 + c * 16 + srow) * K + scol;
  }
  // prologue: k0=0 into buffer 0
#pragma unroll
  for (int p = 0; p < 2; p++) {
    async_ld16(Ap[p], &As[0][coff + p * 512]);
    async_ld16(Bp[p], &Bs[0][coff + p * 512]);
  }
  int buf = 0;
  for (int k0 = 0; k0 < K; k0 += 32) {
    __syncthreads();  // drains vmcnt: buf's loads done; prior reads of buf^1 done
    if (k0 + 32 < K) {
#pragma unroll
      for (int p = 0; p < 2; p++) {
        async_ld16(Ap[p] + k0 + 32, &As[buf ^ 1][coff + p * 512]);
        async_ld16(Bp[p] + k0 + 32, &Bs[buf ^ 1][coff + p * 512]);
      }
    }
    bf16x8 af[4], bf[4];
#pragma unroll
    for (int i = 0; i < 4; i++) {
      __builtin_memcpy(&af[i], &As[buf][(wm + i * 16 + r) * 32 + q * 8], 16);
      __builtin_memcpy(&bf[i], &Bs[buf][(wn + i * 16 + r) * 32 + q * 8], 16);
    }
#pragma unroll
    for (int i = 0; i < 4; i++)
#pragma unroll
      for (int j = 0; j < 4; j++)
        acc[i][j] = __builtin_amdgcn_mfma_f32_16x16x32_bf16(af[i], bf[j], acc[i][j], 0, 0, 0);
    buf ^= 1;
  }
#pragma unroll
  for (int i = 0; i < 4; i++) {
    int mrow = m0 + wm + i * 16 + q * 4;
#pragma unroll
    for (int j = 0; j < 4; j++) {
      int col = n0 + wn + j * 16 + r;
#pragma unroll
      for (int v = 0; v < 4; v++) {
        int m = mrow + v;
        if (m >= M) continue;
        epilogue_store<MODE>(acc[i][j][v], m, col, N, bias, aux, outp);
      }
    }
  }
}

// --------------------------------------------- fallback GEMM 64x64 (B from f32 global)
#define LSTR 72
template <int MODE>
__global__ __launch_bounds__(256) void gemm64(const bf16* __restrict__ A,
                                              const float* __restrict__ Bw,
                                              const float* __restrict__ bias,
                                              const float* __restrict__ aux,
                                              void* __restrict__ outp,
                                              int M, int N, int K, int lda) {
  __shared__ bf16 As[64 * LSTR];
  __shared__ bf16 Bs[64 * LSTR];
  int tid = threadIdx.x;
  int wave = tid >> 6, lane = tid & 63;
  int q = lane >> 4, r = lane & 15;
  int m0 = blockIdx.y * 64, n0 = blockIdx.x * 64;
  int wm = (wave >> 1) * 32, wn = (wave & 1) * 32;
  int a_row = tid >> 2, a_kc = (tid & 3) << 3;
  int b_n = tid & 63, b_kc = (tid >> 6) << 3;
  f32x4 acc[2][2] = {};
  const int agm = m0 + a_row;
  const bool aval = (agm < M);
  const bf16* Ap = A + (size_t)agm * lda + a_kc;
  const long bidx = (long)b_kc * N + n0 + b_n;
  for (int k0 = 0; k0 < K; k0 += 32) {
    uint4 av = make_uint4(0, 0, 0, 0);
    if (aval) __builtin_memcpy(&av, Ap + k0, 16);
    alignas(16) bf16 bvv[8];
    const float* bp = Bw + bidx + (long)k0 * N;
#pragma unroll
    for (int j = 0; j < 8; j++) bvv[j] = (bf16)bp[(long)j * N];
    __syncthreads();
    __builtin_memcpy(&As[a_row * LSTR + a_kc], &av, 16);
    __builtin_memcpy(&Bs[b_n * LSTR + b_kc], bvv, 16);
    __syncthreads();
    bf16x8 af0, af1, bf0, bf1;
    __builtin_memcpy(&af0, &As[(wm + r) * LSTR + q * 8], 16);
    __builtin_memcpy(&af1, &As[(wm + 16 + r) * LSTR + q * 8], 16);
    __builtin_memcpy(&bf0, &Bs[(wn + r) * LSTR + q * 8], 16);
    __builtin_memcpy(&bf1, &Bs[(wn + 16 + r) * LSTR + q * 8], 16);
    acc[0][0] = __builtin_amdgcn_mfma_f32_16x16x32_bf16(af0, bf0, acc[0][0], 0, 0, 0);
    acc[0][1] = __builtin_amdgcn_mfma_f32_16x16x32_bf16(af0, bf1, acc[0][1], 0, 0, 0);
    acc[1][0] = __builtin_amdgcn_mfma_f32_16x16x32_bf16(af1, bf0, acc[1][0], 0, 0, 0);
    acc[1][1] = __builtin_amdgcn_mfma_f32_16x16x32_bf16(af1, bf1, acc[1][1], 0, 0, 0);
  }
#pragma unroll
  for (int i = 0; i < 2; i++) {
#pragma unroll
    for (int jt = 0; jt < 2; jt++) {
      int col = n0 + wn + jt * 16 + r;
#pragma unroll
      for (int v = 0; v < 4; v++) {
        int m = m0 + wm + i * 16 + q * 4 + v;
        if (m >= M) continue;
        epilogue_store<MODE>(acc[i][jt][v], m, col, N, bias, aux, outp);
      }
    }
  }
}

// ------------------------------------------------------- MFMA flash attention
// one block per (b,h); 4 waves, 16-row Q tiles; q pre-scaled 0.125.
// O -> separate attno buffer [ROWS,768] (no in-place aliasing).
#define ANR 224
#define KSTR2 72
#define VSTR 232
__global__ __launch_bounds__(256) void attn_mfma(const bf16* __restrict__ qkv,
                                                 bf16* __restrict__ attno) {
  __shared__ bf16 Ks[ANR * KSTR2];   // 32256 B  [key][hd], rows 197..223 zeroed
  __shared__ bf16 Vt[64 * VSTR];     // 29696 B  [hd][key], keys 197..223 zeroed
  __shared__ bf16 Pb[4][16 * 40];    //  5120 B  per-wave P tile
  int bh = blockIdx.x;
  int b = bh / 12, hh = bh - b * 12;
  int tid = threadIdx.x, wave = tid >> 6, lane = tid & 63;
  int q = lane >> 4, r = lane & 15;
  const bf16* base = qkv + (size_t)(b * S_) * 2304 + hh * 64;
  bf16* obase = attno + (size_t)(b * S_) * 768 + hh * 64;
  for (int ch = tid; ch < S_ * 8; ch += 256) {
    int row = ch >> 3, c8 = (ch & 7) * 8;
    uint4 kv;
    __builtin_memcpy(&kv, base + (size_t)row * 2304 + 768 + c8, 16);
    __builtin_memcpy(&Ks[row * KSTR2 + c8], &kv, 16);
  }
  {  // zero pad Ks rows 197..223 (27 rows x 8 chunks = 216 <= 256 threads)
    alignas(16) bf16 z[8] = {};
    if (tid < 27 * 8) {
      int row = S_ + (tid >> 3), c8 = (tid & 7) * 8;
      __builtin_memcpy(&Ks[row * KSTR2 + c8], z, 16);
    }
  }
  for (int ch = tid; ch < S_ * 8; ch += 256) {
    int row = ch >> 3, c8 = (ch & 7) * 8;
    bf16 tmp[8];
    __builtin_memcpy(tmp, base + (size_t)row * 2304 + 1536 + c8, 16);
#pragma unroll
    for (int e = 0; e < 8; e++) Vt[(c8 + e) * VSTR + row] = tmp[e];
  }
  for (int ch = tid; ch < 27 * 64; ch += 256) {  // zero pad V keys 197..223
    int kk = S_ + ch / 64, hd = ch % 64;
    Vt[hd * VSTR + kk] = (bf16)0.f;
  }
  __syncthreads();
  for (int t = wave; t < 13; t += 4) {
    int q0 = t * 16;
    int qrow = q0 + r;
    if (qrow > S_ - 1) qrow = S_ - 1;
    bf16x8 qa0, qa1;
    __builtin_memcpy(&qa0, base + (size_t)qrow * 2304 + q * 8, 16);
    __builtin_memcpy(&qa1, base + (size_t)qrow * 2304 + 32 + q * 8, 16);
    float m_i[4], l_i[4];
    f32x4 oacc[4] = {};
#pragma unroll
    for (int v = 0; v < 4; v++) { m_i[v] = -1e30f; l_i[v] = 0.f; }
    for (int c0 = 0; c0 < ANR; c0 += 32) {
      f32x4 s0 = {}, s1 = {};
      bf16x8 kb00, kb01, kb10, kb11;
      __builtin_memcpy(&kb00, &Ks[(c0 + r) * KSTR2 + q * 8], 16);
      __builtin_memcpy(&kb01, &Ks[(c0 + r) * KSTR2 + 32 + q * 8], 16);
      __builtin_memcpy(&kb10, &Ks[(c0 + 16 + r) * KSTR2 + q * 8], 16);
      __builtin_memcpy(&kb11, &Ks[(c0 + 16 + r) * KSTR2 + 32 + q * 8], 16);
      s0 = __builtin_amdgcn_mfma_f32_16x16x32_bf16(qa0, kb00, s0, 0, 0, 0);
      s0 = __builtin_amdgcn_mfma_f32_16x16x32_bf16(qa1, kb01, s0, 0, 0, 0);
      s1 = __builtin_amdgcn_mfma_f32_16x16x32_bf16(qa0, kb10, s1, 0, 0, 0);
      s1 = __builtin_amdgcn_mfma_f32_16x16x32_bf16(qa1, kb11, s1, 0, 0, 0);
      if (c0 + r > S_ - 1) { s0[0] = s0[1] = s0[2] = s0[3] = -1e30f; }
      if (c0 + 16 + r > S_ - 1) { s1[0] = s1[1] = s1[2] = s1[3] = -1e30f; }
      float tm[4], al[4], rs[4];
#pragma unroll
      for (int v = 0; v < 4; v++) tm[v] = fmaxf(s0[v], s1[v]);
#pragma unroll
      for (int off = 1; off < 16; off <<= 1)
#pragma unroll
        for (int v = 0; v < 4; v++) tm[v] = fmaxf(tm[v], __shfl_xor(tm[v], off, 64));
      f32x4 p0, p1;
#pragma unroll
      for (int v = 0; v < 4; v++) {
        float mn = fmaxf(m_i[v], tm[v]);
        al[v] = __expf(m_i[v] - mn);
        m_i[v] = mn;
        p0[v] = __expf(s0[v] - mn);
        p1[v] = __expf(s1[v] - mn);
        rs[v] = p0[v] + p1[v];
      }
#pragma unroll
      for (int off = 1; off < 16; off <<= 1)
#pragma unroll
        for (int v = 0; v < 4; v++) rs[v] += __shfl_xor(rs[v], off, 64);
#pragma unroll
      for (int v = 0; v < 4; v++) l_i[v] = l_i[v] * al[v] + rs[v];
#pragma unroll
      for (int nt = 0; nt < 4; nt++)
#pragma unroll
        for (int v = 0; v < 4; v++) oacc[nt][v] *= al[v];
      bf16* pw = &Pb[wave][0];
#pragma unroll
      for (int v = 0; v < 4; v++) {
        pw[(q * 4 + v) * 40 + r] = (bf16)p0[v];
        pw[(q * 4 + v) * 40 + 16 + r] = (bf16)p1[v];
      }
      bf16x8 pa;
      __builtin_memcpy(&pa, &pw[r * 40 + q * 8], 16);
#pragma unroll
      for (int nt = 0; nt < 4; nt++) {
        bf16x8 vb;
        __builtin_memcpy(&vb, &Vt[(nt * 16 + r) * VSTR + c0 + q * 8], 16);
        oacc[nt] = __builtin_amdgcn_mfma_f32_16x16x32_bf16(pa, vb, oacc[nt], 0, 0, 0);
      }
    }
#pragma unroll
    for (int nt = 0; nt < 4; nt++)
#pragma unroll
      for (int v = 0; v < 4; v++) {
        int row = q0 + q * 4 + v;
        if (row <= S_ - 1)
          obase[(size_t)row * 768 + nt * 16 + r] = (bf16)(oacc[nt][v] / l_i[v]);
      }
  }
}

// ------------------------------------------------------------- final LN+head
__global__ __launch_bounds__(256) void head_kernel(const float* __restrict__ x,
                                                   const float* __restrict__ g,
                                                   const float* __restrict__ bb,
                                                   const float* __restrict__ hw,
                                                   const float* __restrict__ hb,
                                                   float* __restrict__ out) {
  int b = blockIdx.x;
  const float* xr = x + (size_t)b * S_ * 768;  // cls row
  int tid = threadIdx.x;
  float v0 = xr[tid], v1 = xr[tid + 256], v2 = xr[tid + 512];
  float a = v0 + v1 + v2;
  float s2 = v0 * v0 + v1 * v1 + v2 * v2;
  for (int off = 32; off; off >>= 1) {
    a += __shfl_down(a, off, 64);
    s2 += __shfl_down(s2, off, 64);
  }
  __shared__ float sa[4], sb[4];
  int wave = tid >> 6;
  if ((tid & 63) == 0) { sa[wave] = a; sb[wave] = s2; }
  __syncthreads();
  float mu = (sa[0] + sa[1] + sa[2] + sa[3]) * (1.f / 768.f);
  float var = (sb[0] + sb[1] + sb[2] + sb[3]) * (1.f / 768.f) - mu * mu;
  float rs = rsqrtf(fmaxf(var, 0.f) + 1e-5f);
  __shared__ float cls[768];
  cls[tid] = (v0 - mu) * rs * g[tid] + bb[tid];
  cls[tid + 256] = (v1 - mu) * rs * g[tid + 256] + bb[tid + 256];
  cls[tid + 512] = (v2 - mu) * rs * g[tid + 512] + bb[tid + 512];
  __syncthreads();
  float p[10];
#pragma unroll
  for (int c = 0; c < 10; c++) p[c] = 0.f;
  for (int e = tid; e < 768; e += 256) {
    float cv = cls[e];
#pragma unroll
    for (int c = 0; c < 10; c++) p[c] += cv * hw[e * 10 + c];
  }
#pragma unroll
  for (int c = 0; c < 10; c++)
    for (int off = 32; off; off >>= 1) p[c] += __shfl_down(p[c], off, 64);
  __shared__ float red[4][10];
  if ((tid & 63) == 0) {
#pragma unroll
    for (int c = 0; c < 10; c++) red[wave][c] = p[c];
  }
  __syncthreads();
  if (tid < 10)
    out[b * 10 + tid] = red[0][tid] + red[1][tid] + red[2][tid] + red[3][tid] + hb[tid];
}

// ------------------------------------------------------------------ launcher
extern "C" void kernel_launch(void* const* d_in, const int* in_sizes, int n_in,
                              void* d_out, int out_size, void* d_ws, size_t ws_size,
                              hipStream_t stream) {
  const float* img     = (const float*)d_in[0];
  const float* patch_w = (const float*)d_in[1];
  const float* patch_b = (const float*)d_in[2];
  const float* cls_t   = (const float*)d_in[3];
  const float* pos     = (const float*)d_in[4];
  const float* qkv_w   = (const float*)d_in[5];
  const float* fc_w    = (const float*)d_in[6];
  const float* mlp_w1  = (const float*)d_in[7];
  const float* mlp_b1  = (const float*)d_in[8];
  const float* mlp_w2  = (const float*)d_in[9];
  const float* mlp_b2  = (const float*)d_in[10];
  const float* ln_g    = (const float*)d_in[11];
  const float* ln_b    = (const float*)d_in[12];
  const float* head_w  = (const float*)d_in[13];
  const float* head_b  = (const float*)d_in[14];

  char* ws = (char*)d_ws;
  // x f32 [6304,768] @0 | h bf16 @19365888 (attno aliases h: h dead after qkv GEMM)
  // | qkv bf16 [6304,2304] @29048832 | wbuf bf16 @58097664 .. 72253440
  float* x   = (float*)ws;
  bf16* h    = (bf16*)(ws + 19365888);
  bf16* qkvb = (bf16*)(ws + 29048832);
  bf16* wbuf = (bf16*)(ws + 58097664);
  bf16* attno = h;       // alias: h is dead once qkv GEMM has consumed it
  bf16* patches = qkvb;  // alias: dead before layer loop
  bf16* mlpbuf  = qkvb;  // alias: qkv dead during MLP

  const bool fast = ws_size >= 72253440ull;

  patchify_kernel<<<PROWS * 768 / 256, 256, 0, stream>>>(img, patches);
  cls_fill_kernel<<<BATCH * 768 / 256, 256, 0, stream>>>(cls_t, pos, x);
  if (fast) {
    convT_single<<<576, 256, 0, stream>>>(patch_w, wbuf, 768, 768);
    gemm128<0><<<dim3(6, 49), 256, 0, stream>>>(patches, wbuf, patch_b, pos, x,
                                                PROWS, 768, 768, 768);
  } else {
    gemm64<0><<<dim3(12, 98), 256, 0, stream>>>(patches, patch_w, patch_b, pos, x,
                                                PROWS, 768, 768, 768);
  }
  for (int l = 0; l < 12; ++l) {
    if (fast)
      convT_layer<<<6912, 256, 0, stream>>>(qkv_w + (size_t)l * 1769472,
                                            fc_w + (size_t)l * 589824,
                                            mlp_w1 + (size_t)l * 2359296,
                                            mlp_w2 + (size_t)l * 2359296, wbuf);
    ln_kernel<<<ROWS, 256, 0, stream>>>(x, h);
    if (fast)
      gemm128<1><<<dim3(18, 50), 256, 0, stream>>>(h, wbuf, nullptr, nullptr, qkvb,
                                                   ROWS, 2304, 768, 768);
    else
      gemm64<1><<<dim3(36, 99), 256, 0, stream>>>(h, qkv_w + (size_t)l * 1769472,
                                                  nullptr, nullptr, qkvb,
                                                  ROWS, 2304, 768, 768);
    attn_mfma<<<BATCH * 12, 256, 0, stream>>>(qkvb, attno);
    if (fast)
      gemm128<2><<<dim3(6, 50), 256, 0, stream>>>(attno, wbuf + 1769472, nullptr,
                                                  nullptr, x, ROWS, 768, 768, 768);
    else
      gemm64<2><<<dim3(12, 99), 256, 0, stream>>>(attno, fc_w + (size_t)l * 589824,
                                                  nullptr, nullptr, x,
                                                  ROWS, 768, 768, 768);
    ln_kernel<<<ROWS, 256, 0, stream>>>(x, h);
    for (int half = 0; half < 2; ++half) {
      const bf16* hh = h + (size_t)half * HROWS * 768;
      float* xh = x + (size_t)half * HROWS * 768;
      if (fast) {
        gemm128<3><<<dim3(24, 25), 256, 0, stream>>>(hh, wbuf + 2359296,
                                                     mlp_b1 + l * 3072, nullptr,
                                                     mlpbuf, HROWS, 3072, 768, 768);
        gemm128<2><<<dim3(6, 25), 256, 0, stream>>>(mlpbuf, wbuf + 4718592,
                                                    mlp_b2 + l * 768, nullptr, xh,
                                                    HROWS, 768, 3072, 3072);
      } else {
        gemm64<3><<<dim3(48, 50), 256, 0, stream>>>(hh, mlp_w1 + (size_t)l * 2359296,
                                                    mlp_b1 + l * 3072, nullptr,
                                                    mlpbuf, HROWS, 3072, 768, 768);
        gemm64<2><<<dim3(12, 50), 256, 0, stream>>>(mlpbuf, mlp_w2 + (size_t)l * 2359296,
                                                    mlp_b2 + l * 768, nullptr, xh,
                                                    HROWS, 768, 3072, 3072);
      }
    }
  }
  head_kernel<<<BATCH, 256, 0, stream>>>(x, ln_g, ln_b, head_w, head_b, (float*)d_out);
}